// Round 1
// baseline (457.534 us; speedup 1.0000x reference)
//
#include <hip/hip_runtime.h>
#include <math.h>

#define NROWS 4096
#define HIDN  512
#define H1N   256
#define H2N   1024
#define NHEAD 4
#define KDIM  256
#define HALFD 128
#define SUBS  512
#define KNN   32

// ---------------- fp32 GEMM: C = act(A(M,K) @ B(N,K)^T + bias) ----------------
// BM=128, BN=64, BK=32, 256 threads, 8x4 micro-tile per thread.
template<int ACT>
__global__ __launch_bounds__(256)
void gemm_bt(const float* __restrict__ A, const float* __restrict__ Bm,
             const float* __restrict__ bias, float* __restrict__ C,
             int M, int N, int K)
{
    __shared__ float As[32][132];
    __shared__ float Bs[32][68];
    const int t  = threadIdx.x;
    const int tx = t & 15, ty = t >> 4;
    const int m0 = blockIdx.x * 128, n0 = blockIdx.y * 64;
    const int r  = t >> 3;        // 0..31
    const int kc = (t & 7) * 4;   // 0,4,..,28

    float acc[8][4];
    #pragma unroll
    for (int i = 0; i < 8; ++i)
        #pragma unroll
        for (int j = 0; j < 4; ++j) acc[i][j] = 0.f;

    for (int kb = 0; kb < K; kb += 32) {
        #pragma unroll
        for (int i = 0; i < 4; ++i) {
            float4 v = *(const float4*)&A[(size_t)(m0 + r + 32*i) * K + kb + kc];
            As[kc+0][r+32*i] = v.x; As[kc+1][r+32*i] = v.y;
            As[kc+2][r+32*i] = v.z; As[kc+3][r+32*i] = v.w;
        }
        #pragma unroll
        for (int i = 0; i < 2; ++i) {
            float4 v = *(const float4*)&Bm[(size_t)(n0 + r + 32*i) * K + kb + kc];
            Bs[kc+0][r+32*i] = v.x; Bs[kc+1][r+32*i] = v.y;
            Bs[kc+2][r+32*i] = v.z; Bs[kc+3][r+32*i] = v.w;
        }
        __syncthreads();
        #pragma unroll
        for (int k = 0; k < 32; ++k) {
            float4 a0 = *(const float4*)&As[k][8*ty];
            float4 a1 = *(const float4*)&As[k][8*ty+4];
            float4 b0 = *(const float4*)&Bs[k][4*tx];
            float av[8] = {a0.x,a0.y,a0.z,a0.w,a1.x,a1.y,a1.z,a1.w};
            float bv[4] = {b0.x,b0.y,b0.z,b0.w};
            #pragma unroll
            for (int i = 0; i < 8; ++i)
                #pragma unroll
                for (int j = 0; j < 4; ++j)
                    acc[i][j] = fmaf(av[i], bv[j], acc[i][j]);
        }
        __syncthreads();
    }

    float4 bb = *(const float4*)&bias[n0 + 4*tx];
    float bz[4] = {bb.x, bb.y, bb.z, bb.w};
    #pragma unroll
    for (int i = 0; i < 8; ++i) {
        float vv[4];
        #pragma unroll
        for (int j = 0; j < 4; ++j) {
            float v = acc[i][j] + bz[j];
            if (ACT == 1) v = v > 0.f ? v : expm1f(v);
            vv[j] = v;
        }
        *(float4*)&C[(size_t)(m0 + 8*ty + i) * N + n0 + 4*tx] =
            make_float4(vv[0], vv[1], vv[2], vv[3]);
    }
}

// ---------------- BatchNorm stats (over batch axis) ----------------
__global__ __launch_bounds__(256)
void bn_partial(const float* __restrict__ h2, float* __restrict__ part)
{
    int col = blockIdx.x * 256 + threadIdx.x;
    int r0  = blockIdx.y * 256;
    float s = 0.f, q = 0.f;
    for (int rr = r0; rr < r0 + 256; ++rr) {
        float v = h2[(size_t)rr * H2N + col];
        s += v; q += v * v;
    }
    part[(size_t)blockIdx.y * H2N + col] = s;
    part[(size_t)16 * H2N + (size_t)blockIdx.y * H2N + col] = q;
}

__global__ __launch_bounds__(256)
void bn_finalize(const float* __restrict__ part, const float* __restrict__ gamma,
                 const float* __restrict__ beta, float* __restrict__ scale,
                 float* __restrict__ shift)
{
    int col = blockIdx.x * 256 + threadIdx.x;
    float s = 0.f, q = 0.f;
    for (int c = 0; c < 16; ++c) {
        s += part[(size_t)c * H2N + col];
        q += part[(size_t)16 * H2N + (size_t)c * H2N + col];
    }
    float mu  = s * (1.f / NROWS);
    float var = q * (1.f / NROWS) - mu * mu;
    float sc  = gamma[col] / sqrtf(var + 1e-5f);
    scale[col] = sc;
    shift[col] = beta[col] - mu * sc;
}

// ---------------- Score GEMM: S[b,h,k] = sum_d qhalf[b,h,d] * keys[h,sub,k,d] ----------------
// BN affine (scale/shift) fused into the A-tile load. BM=128, BN=64, BK=32.
__global__ __launch_bounds__(256)
void score_gemm(const float* __restrict__ h2, const float* __restrict__ keys,
                const float* __restrict__ scale, const float* __restrict__ shift,
                float* __restrict__ s1, float* __restrict__ s2)
{
    __shared__ float As[32][132];
    __shared__ float Bs[32][68];
    const int t  = threadIdx.x;
    const int tx = t & 15, ty = t >> 4;
    const int m0 = blockIdx.x * 128, n0 = blockIdx.y * 64;
    const int z  = blockIdx.z;          // h*2 + sub
    const int h  = z >> 1, sub = z & 1;
    const int cb = h * KDIM + sub * HALFD;   // column base into h2
    const float* Kp = keys + (size_t)z * SUBS * HALFD;  // (512,128)
    float* outb = sub ? s2 : s1;
    const int r  = t >> 3;
    const int kc = (t & 7) * 4;

    float acc[8][4];
    #pragma unroll
    for (int i = 0; i < 8; ++i)
        #pragma unroll
        for (int j = 0; j < 4; ++j) acc[i][j] = 0.f;

    for (int kb = 0; kb < HALFD; kb += 32) {
        float4 sc4 = *(const float4*)&scale[cb + kb + kc];
        float4 sh4 = *(const float4*)&shift[cb + kb + kc];
        #pragma unroll
        for (int i = 0; i < 4; ++i) {
            float4 v = *(const float4*)&h2[(size_t)(m0 + r + 32*i) * H2N + cb + kb + kc];
            v.x = fmaf(v.x, sc4.x, sh4.x);
            v.y = fmaf(v.y, sc4.y, sh4.y);
            v.z = fmaf(v.z, sc4.z, sh4.z);
            v.w = fmaf(v.w, sc4.w, sh4.w);
            As[kc+0][r+32*i] = v.x; As[kc+1][r+32*i] = v.y;
            As[kc+2][r+32*i] = v.z; As[kc+3][r+32*i] = v.w;
        }
        #pragma unroll
        for (int i = 0; i < 2; ++i) {
            float4 v = *(const float4*)&Kp[(size_t)(n0 + r + 32*i) * HALFD + kb + kc];
            Bs[kc+0][r+32*i] = v.x; Bs[kc+1][r+32*i] = v.y;
            Bs[kc+2][r+32*i] = v.z; Bs[kc+3][r+32*i] = v.w;
        }
        __syncthreads();
        #pragma unroll
        for (int k = 0; k < 32; ++k) {
            float4 a0 = *(const float4*)&As[k][8*ty];
            float4 a1 = *(const float4*)&As[k][8*ty+4];
            float4 b0 = *(const float4*)&Bs[k][4*tx];
            float av[8] = {a0.x,a0.y,a0.z,a0.w,a1.x,a1.y,a1.z,a1.w};
            float bv[4] = {b0.x,b0.y,b0.z,b0.w};
            #pragma unroll
            for (int i = 0; i < 8; ++i)
                #pragma unroll
                for (int j = 0; j < 4; ++j)
                    acc[i][j] = fmaf(av[i], bv[j], acc[i][j]);
        }
        __syncthreads();
    }

    // write S[(b*NHEAD + h)*SUBS + n]
    #pragma unroll
    for (int i = 0; i < 8; ++i) {
        int row = m0 + 8*ty + i;
        *(float4*)&outb[((size_t)row * NHEAD + h) * SUBS + n0 + 4*tx] =
            make_float4(acc[i][0], acc[i][1], acc[i][2], acc[i][3]);
    }
}

// ---------------- Top-k + softmax + gather ----------------
// One block per batch row. 4 waves = 4 heads. Wave-argmax iterative top-32
// extraction with jax-compatible tie-breaking (smaller index wins).
__global__ __launch_bounds__(256)
void topk_gather(const float* __restrict__ s1, const float* __restrict__ s2,
                 const float* __restrict__ values, float* __restrict__ out)
{
    const int b    = blockIdx.x;
    const int t    = threadIdx.x;
    const int w    = t >> 6;      // head
    const int lane = t & 63;

    __shared__ float tv[2][NHEAD][KNN];
    __shared__ int   ti[2][NHEAD][KNN];
    __shared__ float wv[NHEAD][KNN];
    __shared__ int   wi[NHEAD][KNN];

    // ---- phase 1: per-head top-32 of s1 and s2 (512 each) ----
    #pragma unroll
    for (int half = 0; half < 2; ++half) {
        const float* row = (half ? s2 : s1) + ((size_t)b * NHEAD + w) * SUBS;
        float v[8];
        #pragma unroll
        for (int j = 0; j < 8; ++j) v[j] = row[lane + 64*j];
        for (int rr = 0; rr < KNN; ++rr) {
            float bv = v[0]; int bj = 0;
            #pragma unroll
            for (int j = 1; j < 8; ++j)
                if (v[j] > bv) { bv = v[j]; bj = j; }
            int bi = lane + 64*bj;
            #pragma unroll
            for (int off = 32; off; off >>= 1) {
                float ov = __shfl_xor(bv, off);
                int   oi = __shfl_xor(bi, off);
                if (ov > bv || (ov == bv && oi < bi)) { bv = ov; bi = oi; }
            }
            if (lane == 0) { tv[half][w][rr] = bv; ti[half][w][rr] = bi; }
            if (lane == (bi & 63)) v[bi >> 6] = -INFINITY;
        }
    }
    __syncthreads();

    // ---- phase 2: top-32 of the 1024 pairwise sums ----
    {
        float cv[16];
        #pragma unroll
        for (int m = 0; m < 16; ++m) {
            int p = lane + 64*m;          // p == i*32 + j  (matches ref order)
            cv[m] = tv[0][w][p >> 5] + tv[1][w][p & 31];
        }
        for (int rr = 0; rr < KNN; ++rr) {
            float bv = cv[0]; int bm = 0;
            #pragma unroll
            for (int m = 1; m < 16; ++m)
                if (cv[m] > bv) { bv = cv[m]; bm = m; }
            int bp = lane + 64*bm;
            #pragma unroll
            for (int off = 32; off; off >>= 1) {
                float ov = __shfl_xor(bv, off);
                int   op = __shfl_xor(bp, off);
                if (ov > bv || (ov == bv && op < bp)) { bv = ov; bp = op; }
            }
            if (lane == 0) {
                wv[w][rr] = bv;
                wi[w][rr] = ti[0][w][bp >> 5] * SUBS + ti[1][w][bp & 31];
            }
            if (lane == (bp & 63)) cv[bp >> 6] = -INFINITY;
        }
    }
    __syncthreads();

    // ---- phase 3: softmax over the 32 selected (wv[w][0] is the max) ----
    {
        float mx = wv[w][0];
        float e  = expf(wv[w][lane & 31] - mx);
        float s  = e;
        #pragma unroll
        for (int off = 16; off; off >>= 1) s += __shfl_xor(s, off);
        if (lane < 32) wv[w][lane] = e / s;
    }
    __syncthreads();

    // ---- phase 4: weighted gather of 128 value rows ----
    float a0 = 0.f, a1 = 0.f;
    #pragma unroll 8
    for (int e = 0; e < NHEAD * KNN; ++e) {
        int hh = e >> 5, rr = e & 31;
        float wgt = wv[hh][rr];
        int row   = wi[hh][rr];
        float2 vv = *(const float2*)&values[(size_t)row * HIDN + 2*t];
        a0 = fmaf(wgt, vv.x, a0);
        a1 = fmaf(wgt, vv.y, a1);
    }
    *(float2*)&out[(size_t)b * HIDN + 2*t] = make_float2(a0, a1);
}

extern "C" void kernel_launch(void* const* d_in, const int* in_sizes, int n_in,
                              void* d_out, int out_size, void* d_ws, size_t ws_size,
                              hipStream_t stream)
{
    const float* x      = (const float*)d_in[0];
    const float* W1     = (const float*)d_in[1];
    const float* b1     = (const float*)d_in[2];
    const float* W2     = (const float*)d_in[3];
    const float* b2     = (const float*)d_in[4];
    const float* gamma  = (const float*)d_in[5];
    const float* beta   = (const float*)d_in[6];
    const float* keys   = (const float*)d_in[7];
    const float* values = (const float*)d_in[8];
    float* out = (float*)d_out;

    float* ws    = (float*)d_ws;
    float* h1    = ws;                                   // 4096*256
    float* h2    = h1 + (size_t)NROWS * H1N;             // 4096*1024
    float* part  = h2 + (size_t)NROWS * H2N;             // 2*16*1024
    float* scale = part + (size_t)2 * 16 * H2N;          // 1024
    float* shift = scale + H2N;                          // 1024
    float* s1    = shift + H2N;                          // 4096*4*512
    float* s2    = s1 + (size_t)NROWS * NHEAD * SUBS;    // 4096*4*512

    // h1 = elu(x @ W1^T + b1)
    gemm_bt<1><<<dim3(NROWS/128, H1N/64), 256, 0, stream>>>(x, W1, b1, h1, NROWS, H1N, HIDN);
    // h2 = h1 @ W2^T + b2
    gemm_bt<0><<<dim3(NROWS/128, H2N/64), 256, 0, stream>>>(h1, W2, b2, h2, NROWS, H2N, H1N);
    // batch-norm stats -> per-column scale/shift
    bn_partial<<<dim3(H2N/256, 16), 256, 0, stream>>>(h2, part);
    bn_finalize<<<dim3(H2N/256), 256, 0, stream>>>(part, gamma, beta, scale, shift);
    // scores (affine fused)
    score_gemm<<<dim3(NROWS/128, SUBS/64, NHEAD*2), 256, 0, stream>>>(h2, keys, scale, shift, s1, s2);
    // top-k + softmax + weighted gather
    topk_gather<<<dim3(NROWS), 256, 0, stream>>>(s1, s2, values, out);
}

// Round 2
// 330.236 us; speedup vs baseline: 1.3855x; 1.3855x over previous
//
#include <hip/hip_runtime.h>
#include <math.h>

#define NROWS 4096
#define HIDN  512
#define H1N   256
#define H2N   1024
#define NHEAD 4
#define KDIM  256
#define HALFD 128
#define SUBS  512
#define KNN   32

// ---------------- DPP wave reduction helpers ----------------
template<int C>
__device__ __forceinline__ float dpp_fmax(float x) {
    int m = __builtin_amdgcn_update_dpp(__float_as_int(x), __float_as_int(x), C, 0xf, 0xf, false);
    return fmaxf(x, __int_as_float(m));
}
__device__ __forceinline__ float wave_fmax_bcast(float x) {
    x = dpp_fmax<0x111>(x);   // row_shr:1
    x = dpp_fmax<0x112>(x);   // row_shr:2
    x = dpp_fmax<0x114>(x);   // row_shr:4
    x = dpp_fmax<0x118>(x);   // row_shr:8
    x = dpp_fmax<0x142>(x);   // row_bcast:15
    x = dpp_fmax<0x143>(x);   // row_bcast:31
    return __int_as_float(__builtin_amdgcn_readlane(__float_as_int(x), 63));
}
template<int C>
__device__ __forceinline__ float dpp_fadd(float x) {
    int m = __builtin_amdgcn_update_dpp(0, __float_as_int(x), C, 0xf, 0xf, true);
    return x + __int_as_float(m);
}
__device__ __forceinline__ float wave_fsum_bcast(float x) {
    x = dpp_fadd<0x111>(x);
    x = dpp_fadd<0x112>(x);
    x = dpp_fadd<0x114>(x);
    x = dpp_fadd<0x118>(x);
    x = dpp_fadd<0x142>(x);
    x = dpp_fadd<0x143>(x);
    return __int_as_float(__builtin_amdgcn_readlane(__float_as_int(x), 63));
}

// staircase slot -> (i,j), slots 0..118 enumerate {(i,j): (i+1)(j+1) <= 32}
__device__ __forceinline__ void slot_to_ij(int s, int& io, int& jo) {
    constexpr int O[32] = {0,32,48,58,66,72,77,81,85,88,91,93,95,97,99,101,
                           103,104,105,106,107,108,109,110,111,112,113,114,115,116,117,118};
    int ii = 0, oo = 0;
    #pragma unroll
    for (int k = 1; k < 32; ++k) {
        bool ge = (s >= O[k]);
        ii += ge ? 1 : 0;
        oo = ge ? O[k] : oo;
    }
    io = ii; jo = s - oo;
}

// ---------------- fp32 GEMM: C = act(A(M,K) @ B(N,K)^T + bias) ----------------
template<int ACT>
__global__ __launch_bounds__(256)
void gemm_bt(const float* __restrict__ A, const float* __restrict__ Bm,
             const float* __restrict__ bias, float* __restrict__ C,
             int M, int N, int K)
{
    __shared__ float As[32][132];
    __shared__ float Bs[32][68];
    const int t  = threadIdx.x;
    const int tx = t & 15, ty = t >> 4;
    const int m0 = blockIdx.x * 128, n0 = blockIdx.y * 64;
    const int r  = t >> 3;
    const int kc = (t & 7) * 4;

    float acc[8][4];
    #pragma unroll
    for (int i = 0; i < 8; ++i)
        #pragma unroll
        for (int j = 0; j < 4; ++j) acc[i][j] = 0.f;

    for (int kb = 0; kb < K; kb += 32) {
        #pragma unroll
        for (int i = 0; i < 4; ++i) {
            float4 v = *(const float4*)&A[(size_t)(m0 + r + 32*i) * K + kb + kc];
            As[kc+0][r+32*i] = v.x; As[kc+1][r+32*i] = v.y;
            As[kc+2][r+32*i] = v.z; As[kc+3][r+32*i] = v.w;
        }
        #pragma unroll
        for (int i = 0; i < 2; ++i) {
            float4 v = *(const float4*)&Bm[(size_t)(n0 + r + 32*i) * K + kb + kc];
            Bs[kc+0][r+32*i] = v.x; Bs[kc+1][r+32*i] = v.y;
            Bs[kc+2][r+32*i] = v.z; Bs[kc+3][r+32*i] = v.w;
        }
        __syncthreads();
        #pragma unroll
        for (int k = 0; k < 32; ++k) {
            float4 a0 = *(const float4*)&As[k][8*ty];
            float4 a1 = *(const float4*)&As[k][8*ty+4];
            float4 b0 = *(const float4*)&Bs[k][4*tx];
            float av[8] = {a0.x,a0.y,a0.z,a0.w,a1.x,a1.y,a1.z,a1.w};
            float bv[4] = {b0.x,b0.y,b0.z,b0.w};
            #pragma unroll
            for (int i = 0; i < 8; ++i)
                #pragma unroll
                for (int j = 0; j < 4; ++j)
                    acc[i][j] = fmaf(av[i], bv[j], acc[i][j]);
        }
        __syncthreads();
    }

    float4 bb = *(const float4*)&bias[n0 + 4*tx];
    float bz[4] = {bb.x, bb.y, bb.z, bb.w};
    #pragma unroll
    for (int i = 0; i < 8; ++i) {
        float vv[4];
        #pragma unroll
        for (int j = 0; j < 4; ++j) {
            float v = acc[i][j] + bz[j];
            if (ACT == 1) v = v > 0.f ? v : expm1f(v);
            vv[j] = v;
        }
        *(float4*)&C[(size_t)(m0 + 8*ty + i) * N + n0 + 4*tx] =
            make_float4(vv[0], vv[1], vv[2], vv[3]);
    }
}

// ---------------- BatchNorm stats ----------------
__global__ __launch_bounds__(256)
void bn_partial(const float* __restrict__ h2, float* __restrict__ part)
{
    int col = blockIdx.x * 256 + threadIdx.x;
    int r0  = blockIdx.y * 256;
    float s = 0.f, q = 0.f;
    for (int rr = r0; rr < r0 + 256; ++rr) {
        float v = h2[(size_t)rr * H2N + col];
        s += v; q += v * v;
    }
    part[(size_t)blockIdx.y * H2N + col] = s;
    part[(size_t)16 * H2N + (size_t)blockIdx.y * H2N + col] = q;
}

__global__ __launch_bounds__(256)
void bn_finalize(const float* __restrict__ part, const float* __restrict__ gamma,
                 const float* __restrict__ beta, float* __restrict__ scale,
                 float* __restrict__ shift)
{
    int col = blockIdx.x * 256 + threadIdx.x;
    float s = 0.f, q = 0.f;
    for (int c = 0; c < 16; ++c) {
        s += part[(size_t)c * H2N + col];
        q += part[(size_t)16 * H2N + (size_t)c * H2N + col];
    }
    float mu  = s * (1.f / NROWS);
    float var = q * (1.f / NROWS) - mu * mu;
    float sc  = gamma[col] / sqrtf(var + 1e-5f);
    scale[col] = sc;
    shift[col] = beta[col] - mu * sc;
}

// ---------------- Score GEMM (BN affine fused) ----------------
__global__ __launch_bounds__(256)
void score_gemm(const float* __restrict__ h2, const float* __restrict__ keys,
                const float* __restrict__ scale, const float* __restrict__ shift,
                float* __restrict__ s1, float* __restrict__ s2)
{
    __shared__ float As[32][132];
    __shared__ float Bs[32][68];
    const int t  = threadIdx.x;
    const int tx = t & 15, ty = t >> 4;
    const int m0 = blockIdx.x * 128, n0 = blockIdx.y * 64;
    const int z  = blockIdx.z;
    const int h  = z >> 1, sub = z & 1;
    const int cb = h * KDIM + sub * HALFD;
    const float* Kp = keys + (size_t)z * SUBS * HALFD;
    float* outb = sub ? s2 : s1;
    const int r  = t >> 3;
    const int kc = (t & 7) * 4;

    float acc[8][4];
    #pragma unroll
    for (int i = 0; i < 8; ++i)
        #pragma unroll
        for (int j = 0; j < 4; ++j) acc[i][j] = 0.f;

    for (int kb = 0; kb < HALFD; kb += 32) {
        float4 sc4 = *(const float4*)&scale[cb + kb + kc];
        float4 sh4 = *(const float4*)&shift[cb + kb + kc];
        #pragma unroll
        for (int i = 0; i < 4; ++i) {
            float4 v = *(const float4*)&h2[(size_t)(m0 + r + 32*i) * H2N + cb + kb + kc];
            v.x = fmaf(v.x, sc4.x, sh4.x);
            v.y = fmaf(v.y, sc4.y, sh4.y);
            v.z = fmaf(v.z, sc4.z, sh4.z);
            v.w = fmaf(v.w, sc4.w, sh4.w);
            As[kc+0][r+32*i] = v.x; As[kc+1][r+32*i] = v.y;
            As[kc+2][r+32*i] = v.z; As[kc+3][r+32*i] = v.w;
        }
        #pragma unroll
        for (int i = 0; i < 2; ++i) {
            float4 v = *(const float4*)&Kp[(size_t)(n0 + r + 32*i) * HALFD + kb + kc];
            Bs[kc+0][r+32*i] = v.x; Bs[kc+1][r+32*i] = v.y;
            Bs[kc+2][r+32*i] = v.z; Bs[kc+3][r+32*i] = v.w;
        }
        __syncthreads();
        #pragma unroll
        for (int k = 0; k < 32; ++k) {
            float4 a0 = *(const float4*)&As[k][8*ty];
            float4 a1 = *(const float4*)&As[k][8*ty+4];
            float4 b0 = *(const float4*)&Bs[k][4*tx];
            float av[8] = {a0.x,a0.y,a0.z,a0.w,a1.x,a1.y,a1.z,a1.w};
            float bv[4] = {b0.x,b0.y,b0.z,b0.w};
            #pragma unroll
            for (int i = 0; i < 8; ++i)
                #pragma unroll
                for (int j = 0; j < 4; ++j)
                    acc[i][j] = fmaf(av[i], bv[j], acc[i][j]);
        }
        __syncthreads();
    }

    #pragma unroll
    for (int i = 0; i < 8; ++i) {
        int row = m0 + 8*ty + i;
        *(float4*)&outb[((size_t)row * NHEAD + h) * SUBS + n0 + 4*tx] =
            make_float4(acc[i][0], acc[i][1], acc[i][2], acc[i][3]);
    }
}

// ---------------- Top-k + softmax + gather (v2: DPP extraction) ----------------
// 512 threads = 8 waves. Phase 1: wave w = task (head*2+half), top-32 of 512
// via per-lane sorted-8 + DPP wave-max extraction. Phase 2: waves 0-3, one head
// each, top-32 over the 119 staircase candidates (i+1)(j+1)<=32. Then softmax
// and a float4 gather split 4 ways over entries.
__global__ __launch_bounds__(512)
void topk_gather(const float* __restrict__ s1, const float* __restrict__ s2,
                 const float* __restrict__ values, float* __restrict__ out)
{
    const int b    = blockIdx.x;
    const int t    = threadIdx.x;
    const int w    = t >> 6;
    const int lane = t & 63;

    __shared__ float t_sh[2*NHEAD][KNN];
    __shared__ int   i_sh[2*NHEAD][KNN];
    __shared__ float sc_sh[NHEAD][KNN];
    __shared__ int   sid_sh[NHEAD][KNN];
    __shared__ float wgt_sh[NHEAD][KNN];
    __shared__ int   idx_sh[NHEAD][KNN];
    __shared__ float4 pacc[4][128];

    // ---- phase 1: one wave per (head,half) task ----
    {
        const int head = w >> 1, half = w & 1;
        const float* srow = (half ? s2 : s1) + ((size_t)b * NHEAD + head) * SUBS;
        float4 va = ((const float4*)srow)[lane * 2];
        float4 vb = ((const float4*)srow)[lane * 2 + 1];
        float v0 = va.x, v1 = va.y, v2 = va.z, v3 = va.w;
        float v4 = vb.x, v5 = vb.y, v6 = vb.z, v7 = vb.w;
        int j0 = lane*8+0, j1 = lane*8+1, j2 = lane*8+2, j3 = lane*8+3;
        int j4 = lane*8+4, j5 = lane*8+5, j6 = lane*8+6, j7 = lane*8+7;

        // Batcher odd-even mergesort, 19 CE, descending
        #define CE(a,b,ia,ib) { bool sw = (a) < (b); \
            float mx = sw ? (b) : (a); float mn = sw ? (a) : (b); \
            int tmx = sw ? (ib) : (ia); int tmn = sw ? (ia) : (ib); \
            a = mx; b = mn; ia = tmx; ib = tmn; }
        CE(v0,v1,j0,j1) CE(v2,v3,j2,j3) CE(v4,v5,j4,j5) CE(v6,v7,j6,j7)
        CE(v0,v2,j0,j2) CE(v1,v3,j1,j3) CE(v4,v6,j4,j6) CE(v5,v7,j5,j7)
        CE(v1,v2,j1,j2) CE(v5,v6,j5,j6)
        CE(v0,v4,j0,j4) CE(v1,v5,j1,j5) CE(v2,v6,j2,j6) CE(v3,v7,j3,j7)
        CE(v2,v4,j2,j4) CE(v3,v5,j3,j5)
        CE(v1,v2,j1,j2) CE(v3,v4,j3,j4) CE(v5,v6,j5,j6)
        #undef CE

        float* trow = t_sh[w];
        int*   irow = i_sh[w];
        for (int rr = 0; rr < KNN; ++rr) {
            float bv = wave_fmax_bcast(v0);
            unsigned long long m = __ballot(v0 == bv);
            int wl = (int)__builtin_ctzll(m);
            if (lane == wl) {
                trow[rr] = v0;
                irow[rr] = j0;
                v0 = v1; v1 = v2; v2 = v3; v3 = v4;
                v4 = v5; v5 = v6; v6 = v7; v7 = -INFINITY;
                j0 = j1; j1 = j2; j2 = j3; j3 = j4;
                j4 = j5; j5 = j6; j6 = j7;
            }
        }
    }
    __syncthreads();

    // ---- phase 2: waves 0..3, one head each ----
    if (w < NHEAD) {
        const int h = w;
        const float* T1 = t_sh[2*h];
        const float* T2 = t_sh[2*h+1];

        int ia, ja, ib2, jb2;
        slot_to_ij(lane, ia, ja);
        float c0 = T1[ia] + T2[ja];
        int id0 = (ia << 5) | ja;
        float c1 = -INFINITY;
        int id1 = 0;
        if (lane + 64 < 119) {
            slot_to_ij(lane + 64, ib2, jb2);
            c1 = T1[ib2] + T2[jb2];
            id1 = (ib2 << 5) | jb2;
        }

        for (int rr = 0; rr < KNN; ++rr) {
            float m = fmaxf(c0, c1);
            float bv = wave_fmax_bcast(m);
            bool f0 = (c0 == bv);
            bool f1 = (c1 == bv);
            unsigned long long msk = __ballot(f0 || f1);
            int wl = (int)__builtin_ctzll(msk);
            if (lane == wl) {
                sc_sh[h][rr]  = bv;
                sid_sh[h][rr] = f0 ? id0 : id1;
                if (f0) c0 = -INFINITY; else c1 = -INFINITY;
            }
        }

        // softmax over the 32 selected (sc_sh[h][0] is the max)
        float scv = sc_sh[h][lane & (KNN-1)];
        float mx  = sc_sh[h][0];
        float e   = (lane < KNN) ? __expf(scv - mx) : 0.f;
        float sden = wave_fsum_bcast(e);
        if (lane < KNN) {
            int kid = sid_sh[h][lane];
            wgt_sh[h][lane] = e / sden;
            idx_sh[h][lane] = i_sh[2*h][kid >> 5] * SUBS + i_sh[2*h+1][kid & 31];
        }
    }
    __syncthreads();

    // ---- phase 3: weighted gather, 4-way entry split, float4 columns ----
    const int sub = t >> 7;        // 0..3
    const int c4  = t & 127;       // float4 column index
    float4 acc = make_float4(0.f, 0.f, 0.f, 0.f);
    #pragma unroll 4
    for (int e4 = 0; e4 < 32; ++e4) {
        int e = (e4 << 2) | sub;
        float wgt = wgt_sh[e >> 5][e & 31];
        int row   = idx_sh[e >> 5][e & 31];
        float4 vv = ((const float4*)(values + (size_t)row * HIDN))[c4];
        acc.x = fmaf(wgt, vv.x, acc.x);
        acc.y = fmaf(wgt, vv.y, acc.y);
        acc.z = fmaf(wgt, vv.z, acc.z);
        acc.w = fmaf(wgt, vv.w, acc.w);
    }
    pacc[sub][c4] = acc;
    __syncthreads();
    if (t < 128) {
        float4 r0 = pacc[0][t], r1 = pacc[1][t], r2 = pacc[2][t], r3 = pacc[3][t];
        float4 r;
        r.x = (r0.x + r1.x) + (r2.x + r3.x);
        r.y = (r0.y + r1.y) + (r2.y + r3.y);
        r.z = (r0.z + r1.z) + (r2.z + r3.z);
        r.w = (r0.w + r1.w) + (r2.w + r3.w);
        ((float4*)(out + (size_t)b * HIDN))[t] = r;
    }
}

extern "C" void kernel_launch(void* const* d_in, const int* in_sizes, int n_in,
                              void* d_out, int out_size, void* d_ws, size_t ws_size,
                              hipStream_t stream)
{
    const float* x      = (const float*)d_in[0];
    const float* W1     = (const float*)d_in[1];
    const float* b1     = (const float*)d_in[2];
    const float* W2     = (const float*)d_in[3];
    const float* b2     = (const float*)d_in[4];
    const float* gamma  = (const float*)d_in[5];
    const float* beta   = (const float*)d_in[6];
    const float* keys   = (const float*)d_in[7];
    const float* values = (const float*)d_in[8];
    float* out = (float*)d_out;

    float* ws    = (float*)d_ws;
    float* h1    = ws;
    float* h2    = h1 + (size_t)NROWS * H1N;
    float* part  = h2 + (size_t)NROWS * H2N;
    float* scale = part + (size_t)2 * 16 * H2N;
    float* shift = scale + H2N;
    float* s1    = shift + H2N;
    float* s2    = s1 + (size_t)NROWS * NHEAD * SUBS;

    gemm_bt<1><<<dim3(NROWS/128, H1N/64), 256, 0, stream>>>(x, W1, b1, h1, NROWS, H1N, HIDN);
    gemm_bt<0><<<dim3(NROWS/128, H2N/64), 256, 0, stream>>>(h1, W2, b2, h2, NROWS, H2N, H1N);
    bn_partial<<<dim3(H2N/256, 16), 256, 0, stream>>>(h2, part);
    bn_finalize<<<dim3(H2N/256), 256, 0, stream>>>(part, gamma, beta, scale, shift);
    score_gemm<<<dim3(NROWS/128, SUBS/64, NHEAD*2), 256, 0, stream>>>(h2, keys, scale, shift, s1, s2);
    topk_gather<<<dim3(NROWS), 512, 0, stream>>>(s1, s2, values, out);
}